// Round 1
// baseline (280.196 us; speedup 1.0000x reference)
//
#include <hip/hip_runtime.h>
#include <hip/hip_bf16.h>
#include <stdint.h>

// Problem dims (fixed by reference)
#define B_ROWS 8192
#define D_DIM  1024
#define C_CLS  1000
#define K_PROT 8
#define N_REAL 8000          // C*K
#define N_PAD  8064          // 63 * 128, zero-padded prototype rows
#define BM 128
#define BN 128
#define BKT 64               // K-tile depth

typedef __attribute__((ext_vector_type(8))) short  short8;   // 8 bf16 (4 VGPRs)
typedef __attribute__((ext_vector_type(4))) float  f32x4;    // MFMA accumulator

// --- helpers -------------------------------------------------------------

__device__ __forceinline__ ushort f2bf(float f) {
    // round-to-nearest-even bf16 (no NaN inputs in this problem)
    union { float f; uint32_t u; } v; v.f = f;
    uint32_t u = v.u;
    return (ushort)((u + 0x7fffu + ((u >> 16) & 1u)) >> 16);
}

typedef __attribute__((address_space(1))) void gv_t;
typedef __attribute__((address_space(3))) void lv_t;

__device__ __forceinline__ void gload_lds16(const void* g, void* l) {
    // async global->LDS, 16B per lane; LDS dest = wave-uniform base + lane*16
    __builtin_amdgcn_global_load_lds((gv_t*)g, (lv_t*)l, 16, 0, 0);
}

__device__ __forceinline__ float waveReduceSum(float s) {
    #pragma unroll
    for (int m = 32; m >= 1; m >>= 1) s += __shfl_xor(s, m);
    return s;
}

// --- kernel 1: normalize weight_v rows -> bf16 z_unit, pad to N_PAD -------

__global__ __launch_bounds__(256) void prep_z(const float* __restrict__ wv,
                                              ushort* __restrict__ zb) {
    const int r = blockIdx.x;          // 0..N_PAD-1
    const int t = threadIdx.x;         // 0..255, 4 floats each
    __shared__ float red[4];

    if (r >= N_REAL) {
        ushort4 z4 = make_ushort4(0, 0, 0, 0);
        ((ushort4*)(zb + (size_t)r * D_DIM))[t] = z4;
        return;
    }
    const float4 v = ((const float4*)(wv + (size_t)r * D_DIM))[t];
    float s = v.x*v.x + v.y*v.y + v.z*v.z + v.w*v.w;
    s = waveReduceSum(s);
    if ((t & 63) == 0) red[t >> 6] = s;
    __syncthreads();
    const float n2 = red[0] + red[1] + red[2] + red[3];
    const float rn = 1.0f / fmaxf(sqrtf(n2), 1e-15f);
    ushort4 o;
    o.x = f2bf(v.x * rn); o.y = f2bf(v.y * rn);
    o.z = f2bf(v.z * rn); o.w = f2bf(v.w * rn);
    ((ushort4*)(zb + (size_t)r * D_DIM))[t] = o;
}

// --- kernel 2: x -> bf16 + cx2 = sum(x^2) ---------------------------------

__global__ __launch_bounds__(256) void prep_x(const float* __restrict__ x,
                                              ushort* __restrict__ xb,
                                              float* __restrict__ cx2) {
    const int b = blockIdx.x;          // 0..B_ROWS-1
    const int t = threadIdx.x;
    __shared__ float red[4];

    const float4 v = ((const float4*)(x + (size_t)b * D_DIM))[t];
    ushort4 o;
    o.x = f2bf(v.x); o.y = f2bf(v.y); o.z = f2bf(v.z); o.w = f2bf(v.w);
    ((ushort4*)(xb + (size_t)b * D_DIM))[t] = o;

    float s = v.x*v.x + v.y*v.y + v.z*v.z + v.w*v.w;
    s = waveReduceSum(s);
    if ((t & 63) == 0) red[t >> 6] = s;
    __syncthreads();
    if (t == 0) cx2[b] = red[0] + red[1] + red[2] + red[3];
}

// --- kernel 3: bf16 MFMA GEMM (M=8192, N=8064pad, K=1024) + fused epilogue

__global__ __launch_bounds__(256, 2) void gemm_epi(
        const ushort* __restrict__ A,    // [B_ROWS][D_DIM] bf16 (x)
        const ushort* __restrict__ Bz,   // [N_PAD][D_DIM] bf16 (z_unit rows)
        const float*  __restrict__ cx2g, // [B_ROWS]
        const float*  __restrict__ wgl,  // [C_CLS]
        const float*  __restrict__ gamma_p,
        float*        __restrict__ out)  // [B_ROWS][C_CLS]
{
    __shared__ __attribute__((aligned(16))) ushort sA[BM * BKT]; // 16 KB
    __shared__ __attribute__((aligned(16))) ushort sB[BN * BKT]; // 16 KB

    const int tid  = threadIdx.x;
    const int lane = tid & 63;
    const int w    = tid >> 6;        // wave 0..3
    const int wr   = w >> 1;          // wave row 0..1 (64 rows each)
    const int wc   = w & 1;           // wave col 0..1 (64 cols each)

    const int bm = blockIdx.x & 63;   // 64 M-tiles
    const int bn = blockIdx.x >> 6;   // 63 N-tiles
    const int m0 = bm * BM;
    const int n0 = bn * BN;

    // staging geometry: each wave covers 32 rows of each tile per K-step,
    // 4 insts x (8 rows x 64 cols); lane -> row = +lane/8, col = (lane&7)*8
    const int stRow = w * 32 + (lane >> 3);
    const int stCol = (lane & 7) * 8;

    // LDS read offsets for fragments (elements)
    const int kOff = (lane >> 4) * 8;
    const ushort* sAr = &sA[(wr * 64 + (lane & 15)) * BKT + kOff];
    const ushort* sBr = &sB[(wc * 64 + (lane & 15)) * BKT + kOff];

    f32x4 acc[4][4];
    #pragma unroll
    for (int mi = 0; mi < 4; ++mi)
        #pragma unroll
        for (int ni = 0; ni < 4; ++ni)
            acc[mi][ni] = (f32x4)(0.0f);

    for (int t = 0; t < D_DIM / BKT; ++t) {
        const int k0 = t * BKT;
        // stage A and B tiles (async, drained by the barrier)
        #pragma unroll
        for (int i = 0; i < 4; ++i) {
            gload_lds16(A  + (size_t)(m0 + stRow + i * 8) * D_DIM + k0 + stCol,
                        &sA[(w * 32 + i * 8) * BKT]);
            gload_lds16(Bz + (size_t)(n0 + stRow + i * 8) * D_DIM + k0 + stCol,
                        &sB[(w * 32 + i * 8) * BKT]);
        }
        __syncthreads();

        #pragma unroll
        for (int kk = 0; kk < 2; ++kk) {
            short8 a[4], b[4];
            #pragma unroll
            for (int mi = 0; mi < 4; ++mi)
                a[mi] = *(const short8*)(sAr + mi * 16 * BKT + kk * 32);
            #pragma unroll
            for (int ni = 0; ni < 4; ++ni)
                b[ni] = *(const short8*)(sBr + ni * 16 * BKT + kk * 32);
            #pragma unroll
            for (int mi = 0; mi < 4; ++mi)
                #pragma unroll
                for (int ni = 0; ni < 4; ++ni)
                    acc[mi][ni] = __builtin_amdgcn_mfma_f32_16x16x32_bf16(
                        a[mi], b[ni], acc[mi][ni], 0, 0, 0);
        }
        __syncthreads();
    }

    // ---- fused epilogue: hyperbolic logits + logsumexp over K=8 ----------
    float* scx = (float*)sA;          // reuse LDS for the cx2 tile
    if (tid < BM) scx[tid] = cx2g[m0 + tid];
    __syncthreads();

    const float gam = gamma_p[0];
    const float ex  = expf(2.0f * gam);
    const float ch2 = ex + 1.0f / ex;           // 2*cosh(2*gamma)
    const float sh  = 0.5f * (ex - 1.0f / ex);  // sinh(2*gamma)

    const int nBase = n0 + wc * 64 + (lane & 15);
    float w2[4]; int cIdx[4];
    #pragma unroll
    for (int ni = 0; ni < 4; ++ni) {
        const int c = (nBase + ni * 16) >> 3;   // class index (k = lane&7)
        cIdx[ni] = c;
        w2[ni] = (c < C_CLS) ? 2.0f * wgl[c] : 0.0f;
    }

    #pragma unroll
    for (int mi = 0; mi < 4; ++mi) {
        #pragma unroll
        for (int r = 0; r < 4; ++r) {
            const int mloc = wr * 64 + mi * 16 + ((lane >> 4) << 2) + r;
            const float c2   = scx[mloc];
            const float p    = (1.0f + c2) * sh;
            const float rden = 1.0f / fmaxf(1.0f - c2, 1e-15f);
            const int   m    = m0 + mloc;
            #pragma unroll
            for (int ni = 0; ni < 4; ++ni) {
                const float v  = acc[mi][ni][r];
                const float tt = fmaf(ch2, v, -p) * rden;   // num/den
                const float at = fabsf(tt);
                // asinh(t) = sign(t)*log(|t| + sqrt(t^2+1))
                const float lg = w2[ni] *
                    copysignf(__logf(at + __fsqrt_rn(fmaf(at, at, 1.0f))), tt);
                // logsumexp over the 8 lanes (k = lane&7) of this class
                float mx = lg;
                mx = fmaxf(mx, __shfl_xor(mx, 1));
                mx = fmaxf(mx, __shfl_xor(mx, 2));
                mx = fmaxf(mx, __shfl_xor(mx, 4));
                float s = __expf(lg - mx);
                s += __shfl_xor(s, 1);
                s += __shfl_xor(s, 2);
                s += __shfl_xor(s, 4);
                if ((lane & 7) == 0 && cIdx[ni] < C_CLS)
                    out[(size_t)m * C_CLS + cIdx[ni]] = mx + __logf(s);
            }
        }
    }
}

// --- launch ----------------------------------------------------------------

extern "C" void kernel_launch(void* const* d_in, const int* in_sizes, int n_in,
                              void* d_out, int out_size, void* d_ws, size_t ws_size,
                              hipStream_t stream) {
    const float* x     = (const float*)d_in[0];
    const float* wv    = (const float*)d_in[1];
    const float* wg    = (const float*)d_in[2];
    const float* gamma = (const float*)d_in[3];
    float* out = (float*)d_out;

    char* ws = (char*)d_ws;
    ushort* xb  = (ushort*)ws;                                  // 16,777,216 B
    ushort* zb  = (ushort*)(ws + (size_t)B_ROWS * D_DIM * 2);   // 16,515,072 B
    float*  cx2 = (float*)(ws + (size_t)B_ROWS * D_DIM * 2
                              + (size_t)N_PAD * D_DIM * 2);     //     32,768 B

    prep_z<<<N_PAD, 256, 0, stream>>>(wv, zb);
    prep_x<<<B_ROWS, 256, 0, stream>>>(x, xb, cx2);
    gemm_epi<<<64 * 63, 256, 0, stream>>>(xb, zb, cx2, wg, gamma, out);
}

// Round 2
// 231.875 us; speedup vs baseline: 1.2084x; 1.2084x over previous
//
#include <hip/hip_runtime.h>
#include <hip/hip_bf16.h>
#include <stdint.h>

// Problem dims (fixed by reference)
#define B_ROWS 8192
#define D_DIM  1024
#define C_CLS  1000
#define K_PROT 8
#define N_REAL 8000          // C*K
#define N_PAD  8064          // 63 * 128, zero-padded prototype rows
#define BM 128
#define BN 128
#define BKT 64               // K-tile depth (elements)

typedef __attribute__((ext_vector_type(8))) short  short8;   // 8 bf16 (4 VGPRs)
typedef __attribute__((ext_vector_type(4))) float  f32x4;    // MFMA accumulator

// --- helpers -------------------------------------------------------------

__device__ __forceinline__ ushort f2bf(float f) {
    union { float f; uint32_t u; } v; v.f = f;
    uint32_t u = v.u;
    return (ushort)((u + 0x7fffu + ((u >> 16) & 1u)) >> 16);
}

typedef __attribute__((address_space(1))) void gv_t;
typedef __attribute__((address_space(3))) void lv_t;

__device__ __forceinline__ void gload_lds16(const void* g, void* l) {
    // async global->LDS, 16B/lane; LDS dest = wave-uniform base + lane*16 (linear!)
    __builtin_amdgcn_global_load_lds((gv_t*)g, (lv_t*)l, 16, 0, 0);
}

__device__ __forceinline__ float waveReduceSum(float s) {
    #pragma unroll
    for (int m = 32; m >= 1; m >>= 1) s += __shfl_xor(s, m);
    return s;
}

// --- kernel 1: normalize weight_v rows -> bf16 z_unit, pad to N_PAD -------

__global__ __launch_bounds__(256) void prep_z(const float* __restrict__ wv,
                                              ushort* __restrict__ zb) {
    const int r = blockIdx.x;
    const int t = threadIdx.x;
    __shared__ float red[4];

    if (r >= N_REAL) {
        ((ushort4*)(zb + (size_t)r * D_DIM))[t] = make_ushort4(0, 0, 0, 0);
        return;
    }
    const float4 v = ((const float4*)(wv + (size_t)r * D_DIM))[t];
    float s = v.x*v.x + v.y*v.y + v.z*v.z + v.w*v.w;
    s = waveReduceSum(s);
    if ((t & 63) == 0) red[t >> 6] = s;
    __syncthreads();
    const float n2 = red[0] + red[1] + red[2] + red[3];
    const float rn = 1.0f / fmaxf(sqrtf(n2), 1e-15f);
    ushort4 o;
    o.x = f2bf(v.x * rn); o.y = f2bf(v.y * rn);
    o.z = f2bf(v.z * rn); o.w = f2bf(v.w * rn);
    ((ushort4*)(zb + (size_t)r * D_DIM))[t] = o;
}

// --- kernel 2: x -> bf16 + cx2 = sum(x^2) ---------------------------------

__global__ __launch_bounds__(256) void prep_x(const float* __restrict__ x,
                                              ushort* __restrict__ xb,
                                              float* __restrict__ cx2) {
    const int b = blockIdx.x;
    const int t = threadIdx.x;
    __shared__ float red[4];

    const float4 v = ((const float4*)(x + (size_t)b * D_DIM))[t];
    ushort4 o;
    o.x = f2bf(v.x); o.y = f2bf(v.y); o.z = f2bf(v.z); o.w = f2bf(v.w);
    ((ushort4*)(xb + (size_t)b * D_DIM))[t] = o;

    float s = v.x*v.x + v.y*v.y + v.z*v.z + v.w*v.w;
    s = waveReduceSum(s);
    if ((t & 63) == 0) red[t >> 6] = s;
    __syncthreads();
    if (t == 0) cx2[b] = red[0] + red[1] + red[2] + red[3];
}

// --- kernel 3: bf16 MFMA GEMM (M=8192, N=8064pad, K=1024) + fused epilogue
//
// T2 LDS swizzle (rule #21: both-sides-or-neither with global_load_lds):
//   LDS dest stays LINEAR; the GLOBAL source column is pre-swizzled so that
//   physical 16B-slot p of row r holds logical 16B-group c = p ^ (r&7);
//   the fragment read applies the same XOR on its byte address.

__global__ __launch_bounds__(256, 2) void gemm_epi(
        const ushort* __restrict__ A,    // [B_ROWS][D_DIM] bf16 (x)
        const ushort* __restrict__ Bz,   // [N_PAD][D_DIM] bf16 (z_unit rows)
        const float*  __restrict__ cx2g, // [B_ROWS]
        const float*  __restrict__ wgl,  // [C_CLS]
        const float*  __restrict__ gamma_p,
        float*        __restrict__ out)  // [B_ROWS][C_CLS]
{
    __shared__ __attribute__((aligned(16))) ushort sA[BM * BKT]; // 16 KB
    __shared__ __attribute__((aligned(16))) ushort sB[BN * BKT]; // 16 KB

    const int tid  = threadIdx.x;
    const int lane = tid & 63;
    const int w    = tid >> 6;        // wave 0..3
    const int wr   = w >> 1;          // wave row 0..1 (64 rows each)
    const int wc   = w & 1;           // wave col 0..1 (64 cols each)

    const int bm = blockIdx.x & 63;   // 64 M-tiles
    const int bn = blockIdx.x >> 6;   // 63 N-tiles
    const int m0 = bm * BM;
    const int n0 = bn * BN;

    // staging: wave covers 32 rows/tile/K-step, 4 insts x (8 rows x 64 cols)
    // lane -> row += lane/8; global col group = (lane&7) ^ (row&7)  [swizzle]
    const int stRow = w * 32 + (lane >> 3);
    const int stCol = ((lane & 7) ^ ((lane >> 3) & 7)) * 8;

    // fragment-read swizzled within-row byte offsets (row&7 == lane&7 for all
    // fragments: rows are (lane&15) + multiples of 16)
    const int swz0 = ((      (lane >> 4) * 16) ^ ((lane & 7) << 4));
    const int swz1 = ((64 + ((lane >> 4) * 16)) ^ ((lane & 7) << 4));
    const char* sAb = (const char*)sA + (wr * 64 + (lane & 15)) * 128;
    const char* sBb = (const char*)sB + (wc * 64 + (lane & 15)) * 128;

    f32x4 acc[4][4];
    #pragma unroll
    for (int mi = 0; mi < 4; ++mi)
        #pragma unroll
        for (int ni = 0; ni < 4; ++ni)
            acc[mi][ni] = (f32x4)(0.0f);

    for (int t = 0; t < D_DIM / BKT; ++t) {
        const int k0 = t * BKT;
        #pragma unroll
        for (int i = 0; i < 4; ++i) {
            gload_lds16(A  + (size_t)(m0 + stRow + i * 8) * D_DIM + k0 + stCol,
                        &sA[(w * 32 + i * 8) * BKT]);
            gload_lds16(Bz + (size_t)(n0 + stRow + i * 8) * D_DIM + k0 + stCol,
                        &sB[(w * 32 + i * 8) * BKT]);
        }
        __syncthreads();

        #pragma unroll
        for (int kk = 0; kk < 2; ++kk) {
            const int swzk = kk ? swz1 : swz0;
            short8 a[4], b[4];
            #pragma unroll
            for (int mi = 0; mi < 4; ++mi)
                a[mi] = *(const short8*)(sAb + mi * 16 * 128 + swzk);
            #pragma unroll
            for (int ni = 0; ni < 4; ++ni)
                b[ni] = *(const short8*)(sBb + ni * 16 * 128 + swzk);
            #pragma unroll
            for (int mi = 0; mi < 4; ++mi)
                #pragma unroll
                for (int ni = 0; ni < 4; ++ni)
                    acc[mi][ni] = __builtin_amdgcn_mfma_f32_16x16x32_bf16(
                        a[mi], b[ni], acc[mi][ni], 0, 0, 0);
        }
        __syncthreads();
    }

    // ---- fused epilogue: hyperbolic logits + logsumexp over K=8 ----------
    float* scx = (float*)sA;          // reuse LDS for the cx2 tile
    if (tid < BM) scx[tid] = cx2g[m0 + tid];
    __syncthreads();

    const float gam = gamma_p[0];
    const float ex  = expf(2.0f * gam);
    const float ch2 = ex + 1.0f / ex;           // 2*cosh(2*gamma)
    const float sh  = 0.5f * (ex - 1.0f / ex);  // sinh(2*gamma)

    const int nBase = n0 + wc * 64 + (lane & 15);
    float w2[4]; int cIdx[4];
    #pragma unroll
    for (int ni = 0; ni < 4; ++ni) {
        const int c = (nBase + ni * 16) >> 3;   // class index (k = lane&7)
        cIdx[ni] = c;
        w2[ni] = (c < C_CLS) ? 2.0f * wgl[c] : 0.0f;
    }

    #pragma unroll
    for (int mi = 0; mi < 4; ++mi) {
        #pragma unroll
        for (int r = 0; r < 4; ++r) {
            const int mloc = wr * 64 + mi * 16 + ((lane >> 4) << 2) + r;
            const float c2   = scx[mloc];
            const float p    = (1.0f + c2) * sh;
            const float rden = 1.0f / fmaxf(1.0f - c2, 1e-15f);
            const int   m    = m0 + mloc;
            #pragma unroll
            for (int ni = 0; ni < 4; ++ni) {
                const float v  = acc[mi][ni][r];
                const float tt = fmaf(ch2, v, -p) * rden;   // num/den
                const float at = fabsf(tt);
                // asinh(t) = sign(t)*log(|t| + sqrt(t^2+1))
                const float lg = w2[ni] *
                    copysignf(__logf(at + __fsqrt_rn(fmaf(at, at, 1.0f))), tt);
                // logsumexp over the 8 lanes (k = lane&7) of this class
                float mx = lg;
                mx = fmaxf(mx, __shfl_xor(mx, 1));
                mx = fmaxf(mx, __shfl_xor(mx, 2));
                mx = fmaxf(mx, __shfl_xor(mx, 4));
                float s = __expf(lg - mx);
                s += __shfl_xor(s, 1);
                s += __shfl_xor(s, 2);
                s += __shfl_xor(s, 4);
                if ((lane & 7) == 0 && cIdx[ni] < C_CLS)
                    out[(size_t)m * C_CLS + cIdx[ni]] = mx + __logf(s);
            }
        }
    }
}

// --- launch ----------------------------------------------------------------

extern "C" void kernel_launch(void* const* d_in, const int* in_sizes, int n_in,
                              void* d_out, int out_size, void* d_ws, size_t ws_size,
                              hipStream_t stream) {
    const float* x     = (const float*)d_in[0];
    const float* wv    = (const float*)d_in[1];
    const float* wg    = (const float*)d_in[2];
    const float* gamma = (const float*)d_in[3];
    float* out = (float*)d_out;

    char* ws = (char*)d_ws;
    ushort* xb  = (ushort*)ws;                                  // 16,777,216 B
    ushort* zb  = (ushort*)(ws + (size_t)B_ROWS * D_DIM * 2);   // 16,515,072 B
    float*  cx2 = (float*)(ws + (size_t)B_ROWS * D_DIM * 2
                              + (size_t)N_PAD * D_DIM * 2);     //     32,768 B

    prep_z<<<N_PAD, 256, 0, stream>>>(wv, zb);
    prep_x<<<B_ROWS, 256, 0, stream>>>(x, xb, cx2);
    gemm_epi<<<64 * 63, 256, 0, stream>>>(xb, zb, cx2, wg, gamma, out);
}

// Round 3
// 174.398 us; speedup vs baseline: 1.6067x; 1.3296x over previous
//
#include <hip/hip_runtime.h>
#include <hip/hip_bf16.h>
#include <stdint.h>

// Problem dims (fixed by reference)
#define B_ROWS 8192
#define D_DIM  1024
#define C_CLS  1000
#define K_PROT 8
#define N_REAL 8000          // C*K
#define N_PAD  8064          // 63 * 128, zero-padded prototype rows
#define BM 128
#define BN 128
#define BKT 64               // K-tile depth (elements)

typedef __attribute__((ext_vector_type(8))) short  short8;   // 8 bf16 (4 VGPRs)
typedef __attribute__((ext_vector_type(4))) float  f32x4;    // MFMA accumulator

// --- helpers -------------------------------------------------------------

__device__ __forceinline__ ushort f2bf(float f) {
    union { float f; uint32_t u; } v; v.f = f;
    uint32_t u = v.u;
    return (ushort)((u + 0x7fffu + ((u >> 16) & 1u)) >> 16);
}

typedef __attribute__((address_space(1))) void gv_t;
typedef __attribute__((address_space(3))) void lv_t;

__device__ __forceinline__ void gload_lds16(const void* g, void* l) {
    // async global->LDS, 16B/lane; LDS dest = wave-uniform base + lane*16 (linear!)
    __builtin_amdgcn_global_load_lds((gv_t*)g, (lv_t*)l, 16, 0, 0);
}

__device__ __forceinline__ float waveReduceSum(float s) {
    #pragma unroll
    for (int m = 32; m >= 1; m >>= 1) s += __shfl_xor(s, m);
    return s;
}

// --- kernel 1: normalize weight_v rows -> bf16, PERMUTED + padded ---------
// Physical column P (0..N_PAD-1) holds logical prototype (class, k) with:
//   bn=P>>7, wc=(P>>6)&1, ni=(P>>4)&3, c=P&15
//   class = bn*16 + wc*8 + (c&7),  k = ni + 4*(c>>3)
// This puts all 8 k of a class into the lane pair (lane, lane^8) of the
// GEMM epilogue -> logsumexp is 2 shuffles per class instead of 48.

__global__ __launch_bounds__(256) void prep_z(const float* __restrict__ wv,
                                              ushort* __restrict__ zb) {
    const int P = blockIdx.x;
    const int t = threadIdx.x;
    __shared__ float red[4];

    const int bn  = P >> 7;
    const int p7  = P & 127;
    const int wc  = (p7 >> 6) & 1;
    const int ni  = (p7 >> 4) & 3;
    const int c   = p7 & 15;
    const int cls = bn * 16 + wc * 8 + (c & 7);
    const int k   = ni + ((c >> 3) << 2);

    if (cls >= C_CLS) {
        ((ushort4*)(zb + (size_t)P * D_DIM))[t] = make_ushort4(0, 0, 0, 0);
        return;
    }
    const int n = cls * K_PROT + k;
    const float4 v = ((const float4*)(wv + (size_t)n * D_DIM))[t];
    float s = v.x*v.x + v.y*v.y + v.z*v.z + v.w*v.w;
    s = waveReduceSum(s);
    if ((t & 63) == 0) red[t >> 6] = s;
    __syncthreads();
    const float n2 = red[0] + red[1] + red[2] + red[3];
    const float rn = 1.0f / fmaxf(sqrtf(n2), 1e-15f);
    ushort4 o;
    o.x = f2bf(v.x * rn); o.y = f2bf(v.y * rn);
    o.z = f2bf(v.z * rn); o.w = f2bf(v.w * rn);
    ((ushort4*)(zb + (size_t)P * D_DIM))[t] = o;
}

// --- kernel 2: x -> bf16 + cx2 = sum(x^2) ---------------------------------

__global__ __launch_bounds__(256) void prep_x(const float* __restrict__ x,
                                              ushort* __restrict__ xb,
                                              float* __restrict__ cx2) {
    const int b = blockIdx.x;
    const int t = threadIdx.x;
    __shared__ float red[4];

    const float4 v = ((const float4*)(x + (size_t)b * D_DIM))[t];
    ushort4 o;
    o.x = f2bf(v.x); o.y = f2bf(v.y); o.z = f2bf(v.z); o.w = f2bf(v.w);
    ((ushort4*)(xb + (size_t)b * D_DIM))[t] = o;

    float s = v.x*v.x + v.y*v.y + v.z*v.z + v.w*v.w;
    s = waveReduceSum(s);
    if ((t & 63) == 0) red[t >> 6] = s;
    __syncthreads();
    if (t == 0) cx2[b] = red[0] + red[1] + red[2] + red[3];
}

// --- kernel 3: bf16 MFMA GEMM (K-loop identical to R2) + cheap epilogue ---

__global__ __launch_bounds__(256, 2) void gemm_epi(
        const ushort* __restrict__ A,    // [B_ROWS][D_DIM] bf16 (x)
        const ushort* __restrict__ Bz,   // [N_PAD][D_DIM] bf16 (permuted z)
        const float*  __restrict__ cx2g, // [B_ROWS]
        const float*  __restrict__ wgl,  // [C_CLS]
        const float*  __restrict__ gamma_p,
        float*        __restrict__ out)  // [B_ROWS][C_CLS]
{
    __shared__ __attribute__((aligned(16))) ushort sA[BM * BKT]; // 16 KB
    __shared__ __attribute__((aligned(16))) ushort sB[BN * BKT]; // 16 KB

    const int tid  = threadIdx.x;
    const int lane = tid & 63;
    const int w    = tid >> 6;        // wave 0..3
    const int wr   = w >> 1;          // wave row 0..1 (64 rows each)
    const int wc   = w & 1;           // wave col 0..1 (64 cols each)

    const int bm = blockIdx.x & 63;   // 64 M-tiles
    const int bn = blockIdx.x >> 6;   // 63 N-tiles
    const int m0 = bm * BM;
    const int n0 = bn * BN;

    // staging: wave covers 32 rows/tile/K-step, 4 insts x (8 rows x 64 cols)
    // global col group = (lane&7) ^ (row&7)   [T2 swizzle, source side]
    const int stRow = w * 32 + (lane >> 3);
    const int stCol = ((lane & 7) ^ ((lane >> 3) & 7)) * 8;

    // fragment-read swizzled within-row byte offsets (row&7 == lane&7)
    const int swz0 = ((      (lane >> 4) * 16) ^ ((lane & 7) << 4));
    const int swz1 = ((64 + ((lane >> 4) * 16)) ^ ((lane & 7) << 4));
    const char* sAb = (const char*)sA + (wr * 64 + (lane & 15)) * 128;
    const char* sBb = (const char*)sB + (wc * 64 + (lane & 15)) * 128;

    f32x4 acc[4][4];
    #pragma unroll
    for (int mi = 0; mi < 4; ++mi)
        #pragma unroll
        for (int ni = 0; ni < 4; ++ni)
            acc[mi][ni] = (f32x4)(0.0f);

    for (int t = 0; t < D_DIM / BKT; ++t) {
        const int k0 = t * BKT;
        #pragma unroll
        for (int i = 0; i < 4; ++i) {
            gload_lds16(A  + (size_t)(m0 + stRow + i * 8) * D_DIM + k0 + stCol,
                        &sA[(w * 32 + i * 8) * BKT]);
            gload_lds16(Bz + (size_t)(n0 + stRow + i * 8) * D_DIM + k0 + stCol,
                        &sB[(w * 32 + i * 8) * BKT]);
        }
        __syncthreads();

        #pragma unroll
        for (int kk = 0; kk < 2; ++kk) {
            const int swzk = kk ? swz1 : swz0;
            short8 a[4], b[4];
            #pragma unroll
            for (int mi = 0; mi < 4; ++mi)
                a[mi] = *(const short8*)(sAb + mi * 16 * 128 + swzk);
            #pragma unroll
            for (int ni = 0; ni < 4; ++ni)
                b[ni] = *(const short8*)(sBb + ni * 16 * 128 + swzk);
            #pragma unroll
            for (int mi = 0; mi < 4; ++mi)
                #pragma unroll
                for (int ni = 0; ni < 4; ++ni)
                    acc[mi][ni] = __builtin_amdgcn_mfma_f32_16x16x32_bf16(
                        a[mi], b[ni], acc[mi][ni], 0, 0, 0);
        }
        __syncthreads();
    }

    // ---- epilogue: lane-pair logsumexp over k --------------------------
    // Column permutation (prep_z): this lane's 4 ni-values are k={0..3} or
    // k={4..7} of class cls; partner lane^8 holds the other half.
    float* scx = (float*)sA;          // reuse LDS for the cx2 tile
    if (tid < BM) scx[tid] = cx2g[m0 + tid];
    __syncthreads();

    const float gam = gamma_p[0];
    const float ex  = expf(2.0f * gam);
    const float ch2 = ex + 1.0f / ex;           // 2*cosh(2*gamma)
    const float sh  = 0.5f * (ex - 1.0f / ex);  // sinh(2*gamma)

    const int  cls = (bn << 4) + (wc << 3) + (lane & 7);
    const bool wrt = ((lane & 8) == 0) && (cls < C_CLS);
    const float w2 = (cls < C_CLS) ? 2.0f * wgl[cls] : 0.0f;

    #pragma unroll
    for (int mi = 0; mi < 4; ++mi) {
        #pragma unroll
        for (int r = 0; r < 4; ++r) {
            const int mloc = wr * 64 + mi * 16 + ((lane >> 4) << 2) + r;
            const float c2   = scx[mloc];
            const float rden = 1.0f / fmaxf(1.0f - c2, 1e-15f);
            const float tc   = ch2 * rden;              // scales inner
            const float tp   = (1.0f + c2) * sh * rden; // subtracted
            float bk[4];
            #pragma unroll
            for (int ni = 0; ni < 4; ++ni) {
                const float t = fmaf(acc[mi][ni][r], tc, -tp);
                // asinh(t) = log(t + sqrt(t^2+1)), valid for all t
                const float u = fmaxf(t + __fsqrt_rn(fmaf(t, t, 1.0f)), 1e-20f);
                bk[ni] = w2 * __logf(u);
            }
            float mx = fmaxf(fmaxf(bk[0], bk[1]), fmaxf(bk[2], bk[3]));
            mx = fmaxf(mx, __shfl_xor(mx, 8));
            float s = __expf(bk[0] - mx) + __expf(bk[1] - mx)
                    + __expf(bk[2] - mx) + __expf(bk[3] - mx);
            s += __shfl_xor(s, 8);
            if (wrt)
                out[(size_t)(m0 + mloc) * C_CLS + cls] = mx + __logf(s);
        }
    }
}

// --- launch ----------------------------------------------------------------

extern "C" void kernel_launch(void* const* d_in, const int* in_sizes, int n_in,
                              void* d_out, int out_size, void* d_ws, size_t ws_size,
                              hipStream_t stream) {
    const float* x     = (const float*)d_in[0];
    const float* wv    = (const float*)d_in[1];
    const float* wg    = (const float*)d_in[2];
    const float* gamma = (const float*)d_in[3];
    float* out = (float*)d_out;

    char* ws = (char*)d_ws;
    ushort* xb  = (ushort*)ws;                                  // 16,777,216 B
    ushort* zb  = (ushort*)(ws + (size_t)B_ROWS * D_DIM * 2);   // 16,515,072 B
    float*  cx2 = (float*)(ws + (size_t)B_ROWS * D_DIM * 2
                              + (size_t)N_PAD * D_DIM * 2);     //     32,768 B

    prep_z<<<N_PAD, 256, 0, stream>>>(wv, zb);
    prep_x<<<B_ROWS, 256, 0, stream>>>(x, xb, cx2);
    gemm_epi<<<64 * 63, 256, 0, stream>>>(xb, zb, cx2, wg, gamma, out);
}